// Round 11
// baseline (1944.592 us; speedup 1.0000x reference)
//
#include <hip/hip_runtime.h>
#include <cstdint>
#include <cstddef>

namespace {

constexpr int kD    = 768;
constexpr int kDI   = 1536;
constexpr int kN    = 16;
constexpr int kDTR  = 48;
constexpr int kL    = 196;
constexpr int kKeep = 49;
constexpr int kB    = 8;
constexpr int kTok  = kB * kKeep;   // 392
constexpr int kPatchRows = kB * kL; // 1568
constexpr float kEps = 1e-5f;

typedef __attribute__((ext_vector_type(8))) short short8;
typedef __attribute__((ext_vector_type(4))) float f32x4;

// f32 -> bf16 round-to-nearest-even
__device__ __forceinline__ short f2bf(float f) {
  unsigned u = __float_as_uint(f);
  return (short)((u + 0x7FFFu + ((u >> 16) & 1u)) >> 16);
}

__device__ __forceinline__ short8 pack8(float4 a, float4 b) {
  short8 r;
  r[0] = f2bf(a.x); r[1] = f2bf(a.y); r[2] = f2bf(a.z); r[3] = f2bf(a.w);
  r[4] = f2bf(b.x); r[5] = f2bf(b.y); r[6] = f2bf(b.z); r[7] = f2bf(b.w);
  return r;
}

__device__ __forceinline__ float silu(float x) { return x / (1.f + expf(-x)); }

// ---------------- block reduction (256 threads = 4 waves) ----------------
__device__ __forceinline__ float block_sum256(float x, float* sbuf) {
#pragma unroll
  for (int o = 32; o > 0; o >>= 1) x += __shfl_down(x, o, 64);
  int wid = threadIdx.x >> 6;
  if ((threadIdx.x & 63) == 0) sbuf[wid] = x;
  __syncthreads();
  float r = sbuf[0] + sbuf[1] + sbuf[2] + sbuf[3];
  __syncthreads();
  return r;
}

// ---------------- im2col for patch embedding ----------------
__global__ __launch_bounds__(256) void im2col_kernel(const float* __restrict__ imgs,
                                                     float* __restrict__ A2) {
  int idx = blockIdx.x * 256 + threadIdx.x;
  if (idx >= kPatchRows * kD) return;
  int col = idx % kD;
  int row = idx / kD;
  int b = row / kL, l = row % kL;
  int gy = l / 14, gx = l % 14;
  int c   = col >> 8;
  int rem = col & 255;
  int py = rem >> 4, px = rem & 15;
  A2[idx] = imgs[((b * 3 + c) * 224 + gy * 16 + py) * 224 + gx * 16 + px];
}

// ---------------- bf16 MFMA GEMM: C[M,N] = A[M,lda] @ W[N,K]^T (+bias) ------
// 64x64 tile, BK=64, 4 waves (2x2), 2x2 x mfma_f32_16x16x32_bf16 per wave.
// SPLIT==1: direct store (+bias). SPLIT>1: partial z -> C + z*M*N (dense).
template <int SPLIT>
__global__ __launch_bounds__(256) void gemm_mfma(const float* __restrict__ A, int lda,
                                                 const float* __restrict__ W,
                                                 const float* __restrict__ bias,
                                                 float* __restrict__ C, int ldc,
                                                 int M, int N, int K) {
  __shared__ __align__(16) short As[8][64][8];
  __shared__ __align__(16) short Bs[8][64][8];
  const int tid = threadIdx.x;
  const int bm = blockIdx.x * 64;
  const int bn = blockIdx.y * 64;
  const int kc = K / SPLIT;
  const int k0 = blockIdx.z * kc;
  const int nk = kc / 64;
  const int sr = tid >> 2;
  const int sq = tid & 3;
  const int lane = tid & 63;
  const int wm = ((tid >> 6) >> 1) * 32;
  const int wn = ((tid >> 6) & 1) * 32;
  const bool mok = (bm + sr) < M;
  const bool nok = (bn + sr) < N;
  const float* Ap = A + (size_t)(bm + sr) * lda + k0 + sq * 16;
  const float* Wp = W + (size_t)(bn + sr) * K + k0 + sq * 16;

  f32x4 acc[2][2];
#pragma unroll
  for (int i = 0; i < 2; ++i)
#pragma unroll
    for (int j = 0; j < 2; ++j) acc[i][j] = (f32x4){0.f, 0.f, 0.f, 0.f};

  for (int kt = 0; kt < nk; ++kt) {
    const int kb = kt * 64;
    const float4 z4 = make_float4(0.f, 0.f, 0.f, 0.f);
    float4 a0 = z4, a1 = z4, a2 = z4, a3 = z4;
    float4 w0 = z4, w1 = z4, w2 = z4, w3 = z4;
    const float* ap = Ap + kb;
    const float* wp = Wp + kb;
    if (mok) {
      a0 = *(const float4*)ap;       a1 = *(const float4*)(ap + 4);
      a2 = *(const float4*)(ap + 8); a3 = *(const float4*)(ap + 12);
    }
    if (nok) {
      w0 = *(const float4*)wp;       w1 = *(const float4*)(wp + 4);
      w2 = *(const float4*)(wp + 8); w3 = *(const float4*)(wp + 12);
    }
    if (kt) __syncthreads();
    *(short8*)&As[sq * 2][sr][0]     = pack8(a0, a1);
    *(short8*)&As[sq * 2 + 1][sr][0] = pack8(a2, a3);
    *(short8*)&Bs[sq * 2][sr][0]     = pack8(w0, w1);
    *(short8*)&Bs[sq * 2 + 1][sr][0] = pack8(w2, w3);
    __syncthreads();
#pragma unroll
    for (int kh = 0; kh < 2; ++kh) {
      const int kg = kh * 4 + (lane >> 4);
      short8 af0 = *(const short8*)&As[kg][wm + (lane & 15)][0];
      short8 af1 = *(const short8*)&As[kg][wm + 16 + (lane & 15)][0];
      short8 bf0 = *(const short8*)&Bs[kg][wn + (lane & 15)][0];
      short8 bf1 = *(const short8*)&Bs[kg][wn + 16 + (lane & 15)][0];
      acc[0][0] = __builtin_amdgcn_mfma_f32_16x16x32_bf16(af0, bf0, acc[0][0], 0, 0, 0);
      acc[0][1] = __builtin_amdgcn_mfma_f32_16x16x32_bf16(af0, bf1, acc[0][1], 0, 0, 0);
      acc[1][0] = __builtin_amdgcn_mfma_f32_16x16x32_bf16(af1, bf0, acc[1][0], 0, 0, 0);
      acc[1][1] = __builtin_amdgcn_mfma_f32_16x16x32_bf16(af1, bf1, acc[1][1], 0, 0, 0);
    }
  }

  const int mrow = (lane >> 4) * 4;
  const int ncol = lane & 15;
#pragma unroll
  for (int i2 = 0; i2 < 2; ++i2)
#pragma unroll
    for (int j2 = 0; j2 < 2; ++j2) {
      int n = bn + wn + j2 * 16 + ncol;
      if (n >= N) continue;
      float bv = (SPLIT == 1 && bias) ? bias[n] : 0.f;
#pragma unroll
      for (int r = 0; r < 4; ++r) {
        int m = bm + wm + i2 * 16 + mrow + r;
        if (m >= M) continue;
        float v = acc[i2][j2][r];
        if (SPLIT == 1) {
          C[(size_t)m * ldc + n] = v + bv;
        } else {
          C[(size_t)blockIdx.z * ((size_t)M * N) + (size_t)m * N + n] = v;
        }
      }
    }
}

// ------- xdbl GEMM with fused depthwise conv+SiLU on the A operand ---------
// xdbl_part[z][m][n] = (silu(conv(xz[:, :1536]))[m, k0:k0+64]) @ xpw[n, k0:k0+64]^T
// M=392, N=80, K=1536 split 24 (one 64-K tile per block).
__global__ __launch_bounds__(256) void gemm_xdbl_conv(const float* __restrict__ xz,
                                                      const float* __restrict__ cw,
                                                      const float* __restrict__ cb,
                                                      const float* __restrict__ W,
                                                      float* __restrict__ Cpart) {
  __shared__ __align__(16) short As[8][64][8];
  __shared__ __align__(16) short Bs[8][64][8];
  const int tid = threadIdx.x;
  const int bm = blockIdx.x * 64;
  const int bn = blockIdx.y * 64;
  const int k0 = blockIdx.z * 64;
  const int sr = tid >> 2;
  const int sq = tid & 3;
  const int lane = tid & 63;
  const int wm = ((tid >> 6) >> 1) * 32;
  const int wn = ((tid >> 6) & 1) * 32;
  const int m = bm + sr;
  const bool mok = m < kTok;
  const bool nok = (bn + sr) < 80;
  const float4 z4 = make_float4(0.f, 0.f, 0.f, 0.f);

  float4 a[4] = {z4, z4, z4, z4};
  if (mok) {
    const int b = m / kKeep, t = m % kKeep;
    const int dbase = k0 + sq * 16;
#pragma unroll
    for (int g = 0; g < 4; ++g) {
      const int d = dbase + g * 4;
      float4 cacc = *(const float4*)&cb[d];
      float4 c0 = *(const float4*)&cw[(d + 0) * 4];  // taps of channel d+0
      float4 c1 = *(const float4*)&cw[(d + 1) * 4];
      float4 c2 = *(const float4*)&cw[(d + 2) * 4];
      float4 c3 = *(const float4*)&cw[(d + 3) * 4];
      const float t0[4] = {c0.x, c0.y, c0.z, c0.w};
      const float t1[4] = {c1.x, c1.y, c1.z, c1.w};
      const float t2[4] = {c2.x, c2.y, c2.z, c2.w};
      const float t3[4] = {c3.x, c3.y, c3.z, c3.w};
#pragma unroll
      for (int j = 0; j < 4; ++j) {
        int tt = t - 3 + j;
        if (tt < 0) continue;
        float4 xv = *(const float4*)&xz[(size_t)(b * kKeep + tt) * 3072 + d];
        cacc.x += xv.x * t0[j];
        cacc.y += xv.y * t1[j];
        cacc.z += xv.z * t2[j];
        cacc.w += xv.w * t3[j];
      }
      cacc.x = silu(cacc.x); cacc.y = silu(cacc.y);
      cacc.z = silu(cacc.z); cacc.w = silu(cacc.w);
      a[g] = cacc;
    }
  }
  float4 w0 = z4, w1 = z4, w2 = z4, w3 = z4;
  if (nok) {
    const float* wp = W + (size_t)(bn + sr) * kDI + k0 + sq * 16;
    w0 = *(const float4*)wp;       w1 = *(const float4*)(wp + 4);
    w2 = *(const float4*)(wp + 8); w3 = *(const float4*)(wp + 12);
  }
  *(short8*)&As[sq * 2][sr][0]     = pack8(a[0], a[1]);
  *(short8*)&As[sq * 2 + 1][sr][0] = pack8(a[2], a[3]);
  *(short8*)&Bs[sq * 2][sr][0]     = pack8(w0, w1);
  *(short8*)&Bs[sq * 2 + 1][sr][0] = pack8(w2, w3);
  __syncthreads();

  f32x4 acc[2][2];
#pragma unroll
  for (int i = 0; i < 2; ++i)
#pragma unroll
    for (int j = 0; j < 2; ++j) acc[i][j] = (f32x4){0.f, 0.f, 0.f, 0.f};
#pragma unroll
  for (int kh = 0; kh < 2; ++kh) {
    const int kg = kh * 4 + (lane >> 4);
    short8 af0 = *(const short8*)&As[kg][wm + (lane & 15)][0];
    short8 af1 = *(const short8*)&As[kg][wm + 16 + (lane & 15)][0];
    short8 bf0 = *(const short8*)&Bs[kg][wn + (lane & 15)][0];
    short8 bf1 = *(const short8*)&Bs[kg][wn + 16 + (lane & 15)][0];
    acc[0][0] = __builtin_amdgcn_mfma_f32_16x16x32_bf16(af0, bf0, acc[0][0], 0, 0, 0);
    acc[0][1] = __builtin_amdgcn_mfma_f32_16x16x32_bf16(af0, bf1, acc[0][1], 0, 0, 0);
    acc[1][0] = __builtin_amdgcn_mfma_f32_16x16x32_bf16(af1, bf0, acc[1][0], 0, 0, 0);
    acc[1][1] = __builtin_amdgcn_mfma_f32_16x16x32_bf16(af1, bf1, acc[1][1], 0, 0, 0);
  }

  const int mrow = (lane >> 4) * 4;
  const int ncol = lane & 15;
#pragma unroll
  for (int i2 = 0; i2 < 2; ++i2)
#pragma unroll
    for (int j2 = 0; j2 < 2; ++j2) {
      int n = bn + wn + j2 * 16 + ncol;
      if (n >= 80) continue;
#pragma unroll
      for (int r = 0; r < 4; ++r) {
        int mm = bm + wm + i2 * 16 + mrow + r;
        if (mm >= kTok) continue;
        Cpart[(size_t)blockIdx.z * (kTok * 80) + (size_t)mm * 80 + n] =
            acc[i2][j2][r];
      }
    }
}

// ---------------- sum split-K partials: out = sum_z part[z] ----------------
__global__ __launch_bounds__(256) void reduce_kernel(const float* __restrict__ part,
                                                     float* __restrict__ out,
                                                     int total4, int Z) {
  int i = blockIdx.x * 256 + threadIdx.x;
  if (i >= total4) return;
  const float4* p = (const float4*)part;
  float4 s = p[i];
  for (int z = 1; z < Z; ++z) {
    float4 v = p[(size_t)z * total4 + i];
    s.x += v.x; s.y += v.y; s.z += v.z; s.w += v.w;
  }
  ((float4*)out)[i] = s;
}

// ---------------- argsort / mask ----------------
__global__ __launch_bounds__(256) void sort_kernel(const float* __restrict__ noise,
                                                   int* __restrict__ ids_keep,
                                                   float* __restrict__ mask_out,
                                                   float* __restrict__ idsr_out) {
  __shared__ float nb[kL];
  int b = blockIdx.x;
  int t = threadIdx.x;
  if (t < kL) nb[t] = noise[b * kL + t];
  __syncthreads();
  if (t < kL) {
    float v = nb[t];
    int rank = 0;
    for (int j = 0; j < kL; ++j) {
      float u = nb[j];
      rank += (u < v || (u == v && j < t)) ? 1 : 0;
    }
    if (rank < kKeep) ids_keep[b * kKeep + rank] = t;
    idsr_out[b * kL + t] = (float)rank;
    mask_out[b * kL + t] = (rank < kKeep) ? 0.f : 1.f;
  }
}

// ---------------- gather kept tokens (+ pos embed) ----------------
__global__ __launch_bounds__(256) void gather_kernel(const float* __restrict__ x0,
                                                     const int* __restrict__ ids_keep,
                                                     const float* __restrict__ pos,
                                                     float* __restrict__ hs) {
  int m = blockIdx.x;
  int b = m / kKeep, k = m % kKeep;
  int l = ids_keep[b * kKeep + k];
  const float* src = x0 + (size_t)(b * kL + l) * kD;
  const float* pp  = pos + (size_t)l * kD;
  float* dst = hs + (size_t)m * kD;
  for (int d = threadIdx.x; d < kD; d += 256) dst[d] = src[d] + pp[d];
}

// ------- res += sum_z part[z] ; out = LN(res)*w + b  (NP partials) ----------
template <int DD, int NP>
__global__ __launch_bounds__(256) void add_ln_kernel(const float* __restrict__ part,
                                                     float* __restrict__ res,
                                                     const float* __restrict__ w,
                                                     const float* __restrict__ b,
                                                     float* __restrict__ out) {
  constexpr int PT = DD / 256;
  __shared__ float sbuf[4];
  int m = blockIdx.x;
  int t = threadIdx.x;
  float v[PT];
  float s = 0.f;
#pragma unroll
  for (int i = 0; i < PT; ++i) {
    int d = t + i * 256;
    float acc = res[(size_t)m * DD + d];
#pragma unroll
    for (int z = 0; z < NP; ++z)
      acc += part[(size_t)z * (kTok * DD) + (size_t)m * DD + d];
    v[i] = acc;
    s += acc;
  }
  float mean = block_sum256(s, sbuf) * (1.f / DD);
  float s2 = 0.f;
#pragma unroll
  for (int i = 0; i < PT; ++i) { float d0 = v[i] - mean; s2 += d0 * d0; }
  float var = block_sum256(s2, sbuf) * (1.f / DD);
  float rstd = rsqrtf(var + kEps);
#pragma unroll
  for (int i = 0; i < PT; ++i) {
    int d = t + i * 256;
    res[(size_t)m * DD + d] = v[i];
    out[(size_t)m * DD + d] = (v[i] - mean) * rstd * w[d] + b[d];
  }
}

// ------ fused conv + dt-GEMM + selective scan; one block per (64-d, b) ------
// dt = softplus(dtr @ dtw^T + dtb); xc = silu(conv(xz)); recurrence over 49 t.
__global__ __launch_bounds__(64) void scan_dt_kernel(const float* __restrict__ xz,
                                                     const float* __restrict__ xdbl,
                                                     const float* __restrict__ cw,
                                                     const float* __restrict__ cb,
                                                     const float* __restrict__ dtw,
                                                     const float* __restrict__ dtbv,
                                                     const float* __restrict__ A_log,
                                                     const float* __restrict__ D_skip,
                                                     float* __restrict__ y) {
  __shared__ __align__(16) float dtr_s[kKeep][kDTR];  // 9408 B
  __shared__ float bcs[kKeep][32];                    // 6272 B
  const int d0 = blockIdx.x * 64;
  const int b  = blockIdx.y;
  const int t  = threadIdx.x;
  for (int i = t; i < kKeep * 80; i += 64) {
    int tt = i / 80, c = i % 80;
    float v = xdbl[(size_t)(b * kKeep + tt) * 80 + c];
    if (c < kDTR) dtr_s[tt][c] = v;
    else bcs[tt][c - kDTR] = v;
  }
  __syncthreads();

  const int d = d0 + t;
  // dtw row in registers (48 floats)
  float4 wreg[12];
#pragma unroll
  for (int q = 0; q < 12; ++q)
    wreg[q] = *(const float4*)&dtw[(size_t)d * kDTR + q * 4];
  float Aloc[kN];
#pragma unroll
  for (int n = 0; n < kN; ++n) Aloc[n] = -expf(A_log[(size_t)d * kN + n]);
  const float dsk = D_skip[d];
  const float dtb0 = dtbv[d];
  const float4 cw4 = *(const float4*)&cw[d * 4];
  const float cb0 = cb[d];

  float s[kN];
#pragma unroll
  for (int n = 0; n < kN; ++n) s[n] = 0.f;
  float w0 = 0.f, w1 = 0.f, w2 = 0.f;  // conv window xz[t-3..t-1]

  for (int tt = 0; tt < kKeep; ++tt) {
    // conv + SiLU
    float xin = xz[(size_t)(b * kKeep + tt) * 3072 + d];
    float cacc = cb0 + w0 * cw4.x + w1 * cw4.y + w2 * cw4.z + xin * cw4.w;
    w0 = w1; w1 = w2; w2 = xin;
    float xcv = silu(cacc);
    // dt
    float dacc = dtb0;
#pragma unroll
    for (int q = 0; q < 12; ++q) {
      float4 r4 = *(const float4*)&dtr_s[tt][q * 4];
      dacc += r4.x * wreg[q].x + r4.y * wreg[q].y +
              r4.z * wreg[q].z + r4.w * wreg[q].w;
    }
    float dtv = (dacc > 20.f) ? dacc : log1pf(expf(dacc));
    float dx = dtv * xcv;
    // B/C for this step into registers
    float4 bc[8];
#pragma unroll
    for (int q = 0; q < 8; ++q) bc[q] = *(const float4*)&bcs[tt][q * 4];
    const float* bf = (const float*)&bc[0];
    float yv = 0.f;
#pragma unroll
    for (int n = 0; n < kN; ++n) {
      float sn = expf(dtv * Aloc[n]) * s[n] + dx * bf[n];
      s[n] = sn;
      yv += sn * bf[16 + n];
    }
    y[(size_t)(b * kKeep + tt) * kDI + d] = yv + dsk * xcv;
  }
}

// ---------------- y2 = (LN(y)*w+b) * silu(z) ----------------
__global__ __launch_bounds__(256) void ssm_ln_silu_kernel(const float* __restrict__ y,
                                                          const float* __restrict__ xz,
                                                          const float* __restrict__ w,
                                                          const float* __restrict__ b,
                                                          float* __restrict__ y2) {
  constexpr int PT = kDI / 256;  // 6
  __shared__ float sbuf[4];
  int m = blockIdx.x;
  int t = threadIdx.x;
  float v[PT];
  float s = 0.f;
#pragma unroll
  for (int i = 0; i < PT; ++i) {
    int d = t + i * 256;
    v[i] = y[(size_t)m * kDI + d];
    s += v[i];
  }
  float mean = block_sum256(s, sbuf) * (1.f / kDI);
  float s2 = 0.f;
#pragma unroll
  for (int i = 0; i < PT; ++i) { float d0 = v[i] - mean; s2 += d0 * d0; }
  float var = block_sum256(s2, sbuf) * (1.f / kDI);
  float rstd = rsqrtf(var + kEps);
#pragma unroll
  for (int i = 0; i < PT; ++i) {
    int d = t + i * 256;
    float z = xz[(size_t)m * 3072 + kDI + d];
    y2[(size_t)m * kDI + d] =
        ((v[i] - mean) * rstd * w[d] + b[d]) * silu(z);
  }
}

}  // namespace

extern "C" void kernel_launch(void* const* d_in, const int* in_sizes, int n_in,
                              void* d_out, int out_size, void* d_ws, size_t ws_size,
                              hipStream_t stream) {
  const float* imgs       = (const float*)d_in[0];
  const float* noise      = (const float*)d_in[1];
  const float* patch_w    = (const float*)d_in[2];
  const float* patch_b    = (const float*)d_in[3];
  const float* pos_embed  = (const float*)d_in[4];
  const float* ln_w       = (const float*)d_in[5];
  const float* ln_b       = (const float*)d_in[6];
  const float* in_proj_w  = (const float*)d_in[7];
  const float* conv_w     = (const float*)d_in[8];
  const float* conv_b     = (const float*)d_in[9];
  const float* x_proj_w   = (const float*)d_in[10];
  const float* dt_w       = (const float*)d_in[11];
  const float* dt_b       = (const float*)d_in[12];
  const float* A_log      = (const float*)d_in[13];
  const float* D_skip     = (const float*)d_in[14];
  const float* ssm_ln_w   = (const float*)d_in[15];
  const float* ssm_ln_b   = (const float*)d_in[16];
  const float* out_proj_w = (const float*)d_in[17];
  const float* final_ln_w = (const float*)d_in[18];
  const float* final_ln_b = (const float*)d_in[19];

  float* out      = (float*)d_out;
  float* latent   = out;                       // 392*768
  float* mask_out = out + 301056;              // 8*196
  float* idsr_out = out + 301056 + 1568;       // 8*196

  // workspace layout (floats)
  float* ws        = (float*)d_ws;
  float* hs        = ws;                    // 301056 (gather output, layer-0 "partial")
  float* res       = hs + 301056;           // 301056
  float* h         = res + 301056;          // 301056
  float* xz        = h + 301056;            // 1204224 (392x3072)
  float* xdbl      = xz + 1204224;          // 31360   (392x80)
  float* part_xdbl = xdbl + 31360;          // 24 x 31360 = 752640
  float* part_out  = part_xdbl + 752640;    // 4 x 301056 = 1204224
  float* ybuf      = part_out + 1204224;    // 602112
  float* y2        = ybuf + 602112;         // 602112
  int*   ids_keep  = (int*)(y2 + 602112);   // 392 ints
  // patch-stage aliases (time-disjoint)
  float* A2 = xz;          // 1568x768 = 1204224, exact fit
  float* x0 = part_xdbl;   // 1568x768 fits in part_xdbl+part_out (1956864)

  // ---- patch embedding: im2col + MFMA GEMM (bias = patch_b) ----
  {
    int tot = kPatchRows * kD;
    im2col_kernel<<<(tot + 255) / 256, 256, 0, stream>>>(imgs, A2);
    gemm_mfma<1><<<dim3(25, 12, 1), 256, 0, stream>>>(
        A2, kD, patch_w, patch_b, x0, kD, kPatchRows, kD, kD);
  }

  // ---- masking (argsort ranks) ----
  sort_kernel<<<kB, 256, 0, stream>>>(noise, ids_keep, mask_out, idsr_out);

  // ---- gather kept tokens + pos embed -> hs ----
  gather_kernel<<<kTok, 256, 0, stream>>>(x0, ids_keep, pos_embed, hs);

  // ---- res = 0 ----
  hipMemsetAsync(res, 0, (size_t)kTok * kD * sizeof(float), stream);

  // ---- 12 Mamba blocks ----
  for (int l = 0; l < 12; ++l) {
    const float* lnw  = ln_w  + (size_t)l * kD;
    const float* lnb  = ln_b  + (size_t)l * kD;
    const float* ipw  = in_proj_w  + (size_t)l * 2 * kDI * kD;
    const float* cw   = conv_w     + (size_t)l * kDI * 4;
    const float* cb   = conv_b     + (size_t)l * kDI;
    const float* xpw  = x_proj_w   + (size_t)l * (kDTR + 2 * kN) * kDI;
    const float* dtw  = dt_w       + (size_t)l * kDI * kDTR;
    const float* dtbv = dt_b       + (size_t)l * kDI;
    const float* alog = A_log      + (size_t)l * kDI * kN;
    const float* dsk  = D_skip     + (size_t)l * kDI;
    const float* slw  = ssm_ln_w   + (size_t)l * kDI;
    const float* slb  = ssm_ln_b   + (size_t)l * kDI;
    const float* opw  = out_proj_w + (size_t)l * kD * kDI;

    // res += (hs | out_proj partials) ; h = LN(res)
    if (l == 0)
      add_ln_kernel<kD, 1><<<kTok, 256, 0, stream>>>(hs, res, lnw, lnb, h);
    else
      add_ln_kernel<kD, 4><<<kTok, 256, 0, stream>>>(part_out, res, lnw, lnb, h);

    // xz = h @ ipw^T   (392 x 3072, K=768)
    gemm_mfma<1><<<dim3(7, 48, 1), 256, 0, stream>>>(
        h, kD, ipw, nullptr, xz, 2 * kDI, kTok, 2 * kDI, kD);

    // xdbl = silu(conv(xz)) @ xpw^T  (392 x 80, K=1536 split 24) + reduce
    gemm_xdbl_conv<<<dim3(7, 2, 24), 256, 0, stream>>>(xz, cw, cb, xpw, part_xdbl);
    reduce_kernel<<<(7840 + 255) / 256, 256, 0, stream>>>(part_xdbl, xdbl, 7840, 24);

    // fused conv + dt + selective scan -> ybuf
    scan_dt_kernel<<<dim3(24, kB), 64, 0, stream>>>(xz, xdbl, cw, cb, dtw, dtbv,
                                                    alog, dsk, ybuf);

    // y2 = (LN(ybuf)*slw+slb) * silu(z)
    ssm_ln_silu_kernel<<<kTok, 256, 0, stream>>>(ybuf, xz, slw, slb, y2);

    // out_proj partials: part_out[z] = y2 @ opw^T (z-th K-quarter)
    gemm_mfma<4><<<dim3(7, 12, 4), 256, 0, stream>>>(
        y2, kDI, opw, nullptr, part_out, kD, kTok, kD, kDI);
  }

  // ---- latent = LN(res + sum part_out) ----
  add_ln_kernel<kD, 4><<<kTok, 256, 0, stream>>>(part_out, res, final_ln_w,
                                                 final_ln_b, latent);
}

// Round 13
// 1378.799 us; speedup vs baseline: 1.4104x; 1.4104x over previous
//
#include <hip/hip_runtime.h>
#include <cstdint>
#include <cstddef>

namespace {

constexpr int kD    = 768;
constexpr int kDI   = 1536;
constexpr int kN    = 16;
constexpr int kDTR  = 48;
constexpr int kL    = 196;
constexpr int kKeep = 49;
constexpr int kB    = 8;
constexpr int kTok  = kB * kKeep;   // 392
constexpr int kPatchRows = kB * kL; // 1568
constexpr float kEps = 1e-5f;

typedef __attribute__((ext_vector_type(8))) short short8;
typedef __attribute__((ext_vector_type(4))) float f32x4;

// f32 -> bf16 round-to-nearest-even
__device__ __forceinline__ short f2bf(float f) {
  unsigned u = __float_as_uint(f);
  return (short)((u + 0x7FFFu + ((u >> 16) & 1u)) >> 16);
}

__device__ __forceinline__ short8 pack8(float4 a, float4 b) {
  short8 r;
  r[0] = f2bf(a.x); r[1] = f2bf(a.y); r[2] = f2bf(a.z); r[3] = f2bf(a.w);
  r[4] = f2bf(b.x); r[5] = f2bf(b.y); r[6] = f2bf(b.z); r[7] = f2bf(b.w);
  return r;
}

__device__ __forceinline__ float silu(float x) { return x / (1.f + expf(-x)); }

// ---------------- block reduction (256 threads = 4 waves) ----------------
__device__ __forceinline__ float block_sum256(float x, float* sbuf) {
#pragma unroll
  for (int o = 32; o > 0; o >>= 1) x += __shfl_down(x, o, 64);
  int wid = threadIdx.x >> 6;
  if ((threadIdx.x & 63) == 0) sbuf[wid] = x;
  __syncthreads();
  float r = sbuf[0] + sbuf[1] + sbuf[2] + sbuf[3];
  __syncthreads();
  return r;
}

// ---------------- im2col for patch embedding ----------------
__global__ __launch_bounds__(256) void im2col_kernel(const float* __restrict__ imgs,
                                                     float* __restrict__ A2) {
  int idx = blockIdx.x * 256 + threadIdx.x;
  if (idx >= kPatchRows * kD) return;
  int col = idx % kD;
  int row = idx / kD;
  int b = row / kL, l = row % kL;
  int gy = l / 14, gx = l % 14;
  int c   = col >> 8;
  int rem = col & 255;
  int py = rem >> 4, px = rem & 15;
  A2[idx] = imgs[((b * 3 + c) * 224 + gy * 16 + py) * 224 + gx * 16 + px];
}

// ---------------- bf16 MFMA GEMM: C[M,N] = act(A[M,lda] @ W[N,K]^T + bias) ----
// 64x64 tile, BK=64, 4 waves (2x2), 2x2 x mfma_f32_16x16x32_bf16 per wave.
// SPLIT==1: direct store (+bias, ACT 1=softplus). SPLIT>1: partial z -> C+z*M*N.
// KG: K-guard (zero-pad K to 64); needs K%4==0.
template <int SPLIT, int ACT, bool KG>
__global__ __launch_bounds__(256) void gemm_mfma(const float* __restrict__ A, int lda,
                                                 const float* __restrict__ W,
                                                 const float* __restrict__ bias,
                                                 float* __restrict__ C, int ldc,
                                                 int M, int N, int K) {
  __shared__ __align__(16) short As[8][64][8];
  __shared__ __align__(16) short Bs[8][64][8];
  const int tid = threadIdx.x;
  const int bm = blockIdx.x * 64;
  const int bn = blockIdx.y * 64;
  const int kc = K / SPLIT;
  const int k0 = blockIdx.z * kc;
  const int nk = (kc + 63) / 64;
  const int sr = tid >> 2;
  const int sq = tid & 3;
  const int lane = tid & 63;
  const int wm = ((tid >> 6) >> 1) * 32;
  const int wn = ((tid >> 6) & 1) * 32;
  const bool mok = (bm + sr) < M;
  const bool nok = (bn + sr) < N;
  const float* Ap = A + (size_t)(bm + sr) * lda + k0 + sq * 16;
  const float* Wp = W + (size_t)(bn + sr) * K + k0 + sq * 16;

  f32x4 acc[2][2];
#pragma unroll
  for (int i = 0; i < 2; ++i)
#pragma unroll
    for (int j = 0; j < 2; ++j) acc[i][j] = (f32x4){0.f, 0.f, 0.f, 0.f};

  for (int kt = 0; kt < nk; ++kt) {
    const int kb = kt * 64;
    const float4 z4 = make_float4(0.f, 0.f, 0.f, 0.f);
    float4 a0 = z4, a1 = z4, a2 = z4, a3 = z4;
    float4 w0 = z4, w1 = z4, w2 = z4, w3 = z4;
    const float* ap = Ap + kb;
    const float* wp = Wp + kb;
    if (!KG) {
      if (mok) {
        a0 = *(const float4*)ap;       a1 = *(const float4*)(ap + 4);
        a2 = *(const float4*)(ap + 8); a3 = *(const float4*)(ap + 12);
      }
      if (nok) {
        w0 = *(const float4*)wp;       w1 = *(const float4*)(wp + 4);
        w2 = *(const float4*)(wp + 8); w3 = *(const float4*)(wp + 12);
      }
    } else {
      const int kq = k0 + kb + sq * 16;
      if (mok) {
        if (kq + 4  <= K) a0 = *(const float4*)ap;
        if (kq + 8  <= K) a1 = *(const float4*)(ap + 4);
        if (kq + 12 <= K) a2 = *(const float4*)(ap + 8);
        if (kq + 16 <= K) a3 = *(const float4*)(ap + 12);
      }
      if (nok) {
        if (kq + 4  <= K) w0 = *(const float4*)wp;
        if (kq + 8  <= K) w1 = *(const float4*)(wp + 4);
        if (kq + 12 <= K) w2 = *(const float4*)(wp + 8);
        if (kq + 16 <= K) w3 = *(const float4*)(wp + 12);
      }
    }
    if (kt) __syncthreads();
    *(short8*)&As[sq * 2][sr][0]     = pack8(a0, a1);
    *(short8*)&As[sq * 2 + 1][sr][0] = pack8(a2, a3);
    *(short8*)&Bs[sq * 2][sr][0]     = pack8(w0, w1);
    *(short8*)&Bs[sq * 2 + 1][sr][0] = pack8(w2, w3);
    __syncthreads();
#pragma unroll
    for (int kh = 0; kh < 2; ++kh) {
      const int kg = kh * 4 + (lane >> 4);
      short8 af0 = *(const short8*)&As[kg][wm + (lane & 15)][0];
      short8 af1 = *(const short8*)&As[kg][wm + 16 + (lane & 15)][0];
      short8 bf0 = *(const short8*)&Bs[kg][wn + (lane & 15)][0];
      short8 bf1 = *(const short8*)&Bs[kg][wn + 16 + (lane & 15)][0];
      acc[0][0] = __builtin_amdgcn_mfma_f32_16x16x32_bf16(af0, bf0, acc[0][0], 0, 0, 0);
      acc[0][1] = __builtin_amdgcn_mfma_f32_16x16x32_bf16(af0, bf1, acc[0][1], 0, 0, 0);
      acc[1][0] = __builtin_amdgcn_mfma_f32_16x16x32_bf16(af1, bf0, acc[1][0], 0, 0, 0);
      acc[1][1] = __builtin_amdgcn_mfma_f32_16x16x32_bf16(af1, bf1, acc[1][1], 0, 0, 0);
    }
  }

  const int mrow = (lane >> 4) * 4;
  const int ncol = lane & 15;
#pragma unroll
  for (int i2 = 0; i2 < 2; ++i2)
#pragma unroll
    for (int j2 = 0; j2 < 2; ++j2) {
      int n = bn + wn + j2 * 16 + ncol;
      if (n >= N) continue;
      float bv = (SPLIT == 1 && bias) ? bias[n] : 0.f;
#pragma unroll
      for (int r = 0; r < 4; ++r) {
        int m = bm + wm + i2 * 16 + mrow + r;
        if (m >= M) continue;
        float v = acc[i2][j2][r];
        if (SPLIT == 1) {
          v += bv;
          if (ACT == 1) v = (v > 20.f) ? v : log1pf(expf(v));
          C[(size_t)m * ldc + n] = v;
        } else {
          C[(size_t)blockIdx.z * ((size_t)M * N) + (size_t)m * N + n] = v;
        }
      }
    }
}

// ------- xdbl GEMM with fused depthwise conv+SiLU on the A operand ---------
// xdbl_part[z][m][n] = (silu(conv(xz[:, :1536]))[m, k0:k0+64]) @ xpw[n, k0:k0+64]^T
__global__ __launch_bounds__(256) void gemm_xdbl_conv(const float* __restrict__ xz,
                                                      const float* __restrict__ cw,
                                                      const float* __restrict__ cb,
                                                      const float* __restrict__ W,
                                                      float* __restrict__ Cpart) {
  __shared__ __align__(16) short As[8][64][8];
  __shared__ __align__(16) short Bs[8][64][8];
  const int tid = threadIdx.x;
  const int bm = blockIdx.x * 64;
  const int bn = blockIdx.y * 64;
  const int k0 = blockIdx.z * 64;
  const int sr = tid >> 2;
  const int sq = tid & 3;
  const int lane = tid & 63;
  const int wm = ((tid >> 6) >> 1) * 32;
  const int wn = ((tid >> 6) & 1) * 32;
  const int m = bm + sr;
  const bool mok = m < kTok;
  const bool nok = (bn + sr) < 80;
  const float4 z4 = make_float4(0.f, 0.f, 0.f, 0.f);

  float4 a[4] = {z4, z4, z4, z4};
  if (mok) {
    const int b = m / kKeep, t = m % kKeep;
    const int dbase = k0 + sq * 16;
#pragma unroll
    for (int g = 0; g < 4; ++g) {
      const int d = dbase + g * 4;
      float4 cacc = *(const float4*)&cb[d];
      float4 c0 = *(const float4*)&cw[(d + 0) * 4];
      float4 c1 = *(const float4*)&cw[(d + 1) * 4];
      float4 c2 = *(const float4*)&cw[(d + 2) * 4];
      float4 c3 = *(const float4*)&cw[(d + 3) * 4];
      const float t0[4] = {c0.x, c0.y, c0.z, c0.w};
      const float t1[4] = {c1.x, c1.y, c1.z, c1.w};
      const float t2[4] = {c2.x, c2.y, c2.z, c2.w};
      const float t3[4] = {c3.x, c3.y, c3.z, c3.w};
#pragma unroll
      for (int j = 0; j < 4; ++j) {
        int tt = t - 3 + j;
        if (tt < 0) continue;
        float4 xv = *(const float4*)&xz[(size_t)(b * kKeep + tt) * 3072 + d];
        cacc.x += xv.x * t0[j];
        cacc.y += xv.y * t1[j];
        cacc.z += xv.z * t2[j];
        cacc.w += xv.w * t3[j];
      }
      cacc.x = silu(cacc.x); cacc.y = silu(cacc.y);
      cacc.z = silu(cacc.z); cacc.w = silu(cacc.w);
      a[g] = cacc;
    }
  }
  float4 w0 = z4, w1 = z4, w2 = z4, w3 = z4;
  if (nok) {
    const float* wp = W + (size_t)(bn + sr) * kDI + k0 + sq * 16;
    w0 = *(const float4*)wp;       w1 = *(const float4*)(wp + 4);
    w2 = *(const float4*)(wp + 8); w3 = *(const float4*)(wp + 12);
  }
  *(short8*)&As[sq * 2][sr][0]     = pack8(a[0], a[1]);
  *(short8*)&As[sq * 2 + 1][sr][0] = pack8(a[2], a[3]);
  *(short8*)&Bs[sq * 2][sr][0]     = pack8(w0, w1);
  *(short8*)&Bs[sq * 2 + 1][sr][0] = pack8(w2, w3);
  __syncthreads();

  f32x4 acc[2][2];
#pragma unroll
  for (int i = 0; i < 2; ++i)
#pragma unroll
    for (int j = 0; j < 2; ++j) acc[i][j] = (f32x4){0.f, 0.f, 0.f, 0.f};
#pragma unroll
  for (int kh = 0; kh < 2; ++kh) {
    const int kg = kh * 4 + (lane >> 4);
    short8 af0 = *(const short8*)&As[kg][wm + (lane & 15)][0];
    short8 af1 = *(const short8*)&As[kg][wm + 16 + (lane & 15)][0];
    short8 bf0 = *(const short8*)&Bs[kg][wn + (lane & 15)][0];
    short8 bf1 = *(const short8*)&Bs[kg][wn + 16 + (lane & 15)][0];
    acc[0][0] = __builtin_amdgcn_mfma_f32_16x16x32_bf16(af0, bf0, acc[0][0], 0, 0, 0);
    acc[0][1] = __builtin_amdgcn_mfma_f32_16x16x32_bf16(af0, bf1, acc[0][1], 0, 0, 0);
    acc[1][0] = __builtin_amdgcn_mfma_f32_16x16x32_bf16(af1, bf0, acc[1][0], 0, 0, 0);
    acc[1][1] = __builtin_amdgcn_mfma_f32_16x16x32_bf16(af1, bf1, acc[1][1], 0, 0, 0);
  }

  const int mrow = (lane >> 4) * 4;
  const int ncol = lane & 15;
#pragma unroll
  for (int i2 = 0; i2 < 2; ++i2)
#pragma unroll
    for (int j2 = 0; j2 < 2; ++j2) {
      int n = bn + wn + j2 * 16 + ncol;
      if (n >= 80) continue;
#pragma unroll
      for (int r = 0; r < 4; ++r) {
        int mm = bm + wm + i2 * 16 + mrow + r;
        if (mm >= kTok) continue;
        Cpart[(size_t)blockIdx.z * (kTok * 80) + (size_t)mm * 80 + n] =
            acc[i2][j2][r];
      }
    }
}

// ---------------- sum split-K partials: out = sum_z part[z] ----------------
__global__ __launch_bounds__(256) void reduce_kernel(const float* __restrict__ part,
                                                     float* __restrict__ out,
                                                     int total4, int Z) {
  int i = blockIdx.x * 256 + threadIdx.x;
  if (i >= total4) return;
  const float4* p = (const float4*)part;
  float4 s = p[i];
  for (int z = 1; z < Z; ++z) {
    float4 v = p[(size_t)z * total4 + i];
    s.x += v.x; s.y += v.y; s.z += v.z; s.w += v.w;
  }
  ((float4*)out)[i] = s;
}

// ---------------- argsort / mask ----------------
__global__ __launch_bounds__(256) void sort_kernel(const float* __restrict__ noise,
                                                   int* __restrict__ ids_keep,
                                                   float* __restrict__ mask_out,
                                                   float* __restrict__ idsr_out) {
  __shared__ float nb[kL];
  int b = blockIdx.x;
  int t = threadIdx.x;
  if (t < kL) nb[t] = noise[b * kL + t];
  __syncthreads();
  if (t < kL) {
    float v = nb[t];
    int rank = 0;
    for (int j = 0; j < kL; ++j) {
      float u = nb[j];
      rank += (u < v || (u == v && j < t)) ? 1 : 0;
    }
    if (rank < kKeep) ids_keep[b * kKeep + rank] = t;
    idsr_out[b * kL + t] = (float)rank;
    mask_out[b * kL + t] = (rank < kKeep) ? 0.f : 1.f;
  }
}

// ---------------- gather kept tokens (+ pos embed) ----------------
__global__ __launch_bounds__(256) void gather_kernel(const float* __restrict__ x0,
                                                     const int* __restrict__ ids_keep,
                                                     const float* __restrict__ pos,
                                                     float* __restrict__ hs) {
  int m = blockIdx.x;
  int b = m / kKeep, k = m % kKeep;
  int l = ids_keep[b * kKeep + k];
  const float* src = x0 + (size_t)(b * kL + l) * kD;
  const float* pp  = pos + (size_t)l * kD;
  float* dst = hs + (size_t)m * kD;
  for (int d = threadIdx.x; d < kD; d += 256) dst[d] = src[d] + pp[d];
}

// ------- res += sum_z part[z] ; out = LN(res)*w + b  (NP partials) ----------
template <int DD, int NP>
__global__ __launch_bounds__(256) void add_ln_kernel(const float* __restrict__ part,
                                                     float* __restrict__ res,
                                                     const float* __restrict__ w,
                                                     const float* __restrict__ b,
                                                     float* __restrict__ out) {
  constexpr int PT = DD / 256;
  __shared__ float sbuf[4];
  int m = blockIdx.x;
  int t = threadIdx.x;
  float v[PT];
  float s = 0.f;
#pragma unroll
  for (int i = 0; i < PT; ++i) {
    int d = t + i * 256;
    float acc = res[(size_t)m * DD + d];
#pragma unroll
    for (int z = 0; z < NP; ++z)
      acc += part[(size_t)z * (kTok * DD) + (size_t)m * DD + d];
    v[i] = acc;
    s += acc;
  }
  float mean = block_sum256(s, sbuf) * (1.f / DD);
  float s2 = 0.f;
#pragma unroll
  for (int i = 0; i < PT; ++i) { float d0 = v[i] - mean; s2 += d0 * d0; }
  float var = block_sum256(s2, sbuf) * (1.f / DD);
  float rstd = rsqrtf(var + kEps);
#pragma unroll
  for (int i = 0; i < PT; ++i) {
    int d = t + i * 256;
    res[(size_t)m * DD + d] = v[i];
    out[(size_t)m * DD + d] = (v[i] - mean) * rstd * w[d] + b[d];
  }
}

// ------ state-parallel selective scan: thread = (channel, state) -----------
// block = 16 ch x 16 states = 256 thr; grid = (1536/16, 8) = 768 blocks.
// conv+SiLU recomputed per lane (redundant x16, cheap); y reduced over the
// 16-state lane group via shfl_xor; coalesced LDS-staged IO.
__global__ __launch_bounds__(256) void scan_state_kernel(
    const float* __restrict__ dt,    // [392][1536] softplus'd
    const float* __restrict__ xz,    // [392][3072] (x half)
    const float* __restrict__ xdbl,  // [392][80] (B/C at 48..79)
    const float* __restrict__ cw, const float* __restrict__ cb,
    const float* __restrict__ A_log, const float* __restrict__ D_skip,
    float* __restrict__ y) {
  __shared__ float dts[kKeep][16];
  __shared__ float xzs[kKeep][16];
  __shared__ float bcs[kKeep][32];
  __shared__ float ys[kKeep][16];
  const int d0 = blockIdx.x * 16;
  const int b  = blockIdx.y;
  const int tid = threadIdx.x;
  for (int i = tid; i < kKeep * 16; i += 256) {
    int t = i >> 4, c = i & 15;
    dts[t][c] = dt[(size_t)(b * kKeep + t) * kDI + d0 + c];
    xzs[t][c] = xz[(size_t)(b * kKeep + t) * 3072 + d0 + c];
  }
  for (int i = tid; i < kKeep * 32; i += 256) {
    int t = i >> 5, c = i & 31;
    bcs[t][c] = xdbl[(size_t)(b * kKeep + t) * 80 + kDTR + c];
  }
  __syncthreads();

  const int ch = tid >> 4;   // 0..15 channel within block
  const int n  = tid & 15;   // state
  const int d  = d0 + ch;
  const float Aval = -expf(A_log[(size_t)d * kN + n]);
  const float dsk  = D_skip[d];
  const float4 cw4 = *(const float4*)&cw[d * 4];
  const float cb0  = cb[d];

  float s = 0.f;
  float w0 = 0.f, w1 = 0.f, w2 = 0.f;  // conv window
  for (int t = 0; t < kKeep; ++t) {
    float xin = xzs[t][ch];
    float cacc = cb0 + w0 * cw4.x + w1 * cw4.y + w2 * cw4.z + xin * cw4.w;
    w0 = w1; w1 = w2; w2 = xin;
    float xcv = silu(cacc);
    float dtv = dts[t][ch];
    s = expf(dtv * Aval) * s + (dtv * xcv) * bcs[t][n];
    float yp = s * bcs[t][16 + n];
    yp += __shfl_xor(yp, 1, 64);
    yp += __shfl_xor(yp, 2, 64);
    yp += __shfl_xor(yp, 4, 64);
    yp += __shfl_xor(yp, 8, 64);
    if (n == 0) ys[t][ch] = yp + dsk * xcv;
  }
  __syncthreads();
  for (int i = tid; i < kKeep * 16; i += 256)
    y[(size_t)(b * kKeep + (i >> 4)) * kDI + d0 + (i & 15)] = ys[i >> 4][i & 15];
}

// ---------------- y2 = (LN(y)*w+b) * silu(z) ----------------
__global__ __launch_bounds__(256) void ssm_ln_silu_kernel(const float* __restrict__ y,
                                                          const float* __restrict__ xz,
                                                          const float* __restrict__ w,
                                                          const float* __restrict__ b,
                                                          float* __restrict__ y2) {
  constexpr int PT = kDI / 256;  // 6
  __shared__ float sbuf[4];
  int m = blockIdx.x;
  int t = threadIdx.x;
  float v[PT];
  float s = 0.f;
#pragma unroll
  for (int i = 0; i < PT; ++i) {
    int d = t + i * 256;
    v[i] = y[(size_t)m * kDI + d];
    s += v[i];
  }
  float mean = block_sum256(s, sbuf) * (1.f / kDI);
  float s2 = 0.f;
#pragma unroll
  for (int i = 0; i < PT; ++i) { float d0 = v[i] - mean; s2 += d0 * d0; }
  float var = block_sum256(s2, sbuf) * (1.f / kDI);
  float rstd = rsqrtf(var + kEps);
#pragma unroll
  for (int i = 0; i < PT; ++i) {
    int d = t + i * 256;
    float z = xz[(size_t)m * 3072 + kDI + d];
    y2[(size_t)m * kDI + d] =
        ((v[i] - mean) * rstd * w[d] + b[d]) * silu(z);
  }
}

}  // namespace

extern "C" void kernel_launch(void* const* d_in, const int* in_sizes, int n_in,
                              void* d_out, int out_size, void* d_ws, size_t ws_size,
                              hipStream_t stream) {
  const float* imgs       = (const float*)d_in[0];
  const float* noise      = (const float*)d_in[1];
  const float* patch_w    = (const float*)d_in[2];
  const float* patch_b    = (const float*)d_in[3];
  const float* pos_embed  = (const float*)d_in[4];
  const float* ln_w       = (const float*)d_in[5];
  const float* ln_b       = (const float*)d_in[6];
  const float* in_proj_w  = (const float*)d_in[7];
  const float* conv_w     = (const float*)d_in[8];
  const float* conv_b     = (const float*)d_in[9];
  const float* x_proj_w   = (const float*)d_in[10];
  const float* dt_w       = (const float*)d_in[11];
  const float* dt_b       = (const float*)d_in[12];
  const float* A_log      = (const float*)d_in[13];
  const float* D_skip     = (const float*)d_in[14];
  const float* ssm_ln_w   = (const float*)d_in[15];
  const float* ssm_ln_b   = (const float*)d_in[16];
  const float* out_proj_w = (const float*)d_in[17];
  const float* final_ln_w = (const float*)d_in[18];
  const float* final_ln_b = (const float*)d_in[19];

  float* out      = (float*)d_out;
  float* latent   = out;                       // 392*768
  float* mask_out = out + 301056;              // 8*196
  float* idsr_out = out + 301056 + 1568;       // 8*196

  // workspace layout (floats)
  float* ws        = (float*)d_ws;
  float* hs        = ws;                    // 301056 (gather out, layer-0 "partial")
  float* res       = hs + 301056;           // 301056
  float* h         = res + 301056;          // 301056
  float* xz        = h + 301056;            // 1204224 (392x3072)
  float* xdbl      = xz + 1204224;          // 31360   (392x80)
  float* dtb_      = xdbl + 31360;          // 602112  (392x1536)
  float* part_xdbl = dtb_ + 602112;         // 24 x 31360 = 752640
  float* part_out  = part_xdbl + 752640;    // 4 x 301056 = 1204224
  float* ybuf      = part_out + 1204224;    // 602112
  float* y2        = ybuf + 602112;         // 602112
  int*   ids_keep  = (int*)(y2 + 602112);   // 392 ints
  // patch-stage aliases (time-disjoint)
  float* A2 = xz;          // 1568x768 = 1204224, exact fit
  float* x0 = part_xdbl;   // 1568x768 fits in part_xdbl+part_out (1956864)

  // ---- patch embedding: im2col + MFMA GEMM (bias = patch_b) ----
  {
    int tot = kPatchRows * kD;
    im2col_kernel<<<(tot + 255) / 256, 256, 0, stream>>>(imgs, A2);
    gemm_mfma<1, 0, false><<<dim3(25, 12, 1), 256, 0, stream>>>(
        A2, kD, patch_w, patch_b, x0, kD, kPatchRows, kD, kD);
  }

  // ---- masking (argsort ranks) ----
  sort_kernel<<<kB, 256, 0, stream>>>(noise, ids_keep, mask_out, idsr_out);

  // ---- gather kept tokens + pos embed -> hs ----
  gather_kernel<<<kTok, 256, 0, stream>>>(x0, ids_keep, pos_embed, hs);

  // ---- res = 0 ----
  hipMemsetAsync(res, 0, (size_t)kTok * kD * sizeof(float), stream);

  // ---- 12 Mamba blocks ----
  for (int l = 0; l < 12; ++l) {
    const float* lnw  = ln_w  + (size_t)l * kD;
    const float* lnb  = ln_b  + (size_t)l * kD;
    const float* ipw  = in_proj_w  + (size_t)l * 2 * kDI * kD;
    const float* cw   = conv_w     + (size_t)l * kDI * 4;
    const float* cb   = conv_b     + (size_t)l * kDI;
    const float* xpw  = x_proj_w   + (size_t)l * (kDTR + 2 * kN) * kDI;
    const float* dtw  = dt_w       + (size_t)l * kDI * kDTR;
    const float* dtbv = dt_b       + (size_t)l * kDI;
    const float* alog = A_log      + (size_t)l * kDI * kN;
    const float* dsk  = D_skip     + (size_t)l * kDI;
    const float* slw  = ssm_ln_w   + (size_t)l * kDI;
    const float* slb  = ssm_ln_b   + (size_t)l * kDI;
    const float* opw  = out_proj_w + (size_t)l * kD * kDI;

    // res += (hs | out_proj partials) ; h = LN(res)
    if (l == 0)
      add_ln_kernel<kD, 1><<<kTok, 256, 0, stream>>>(hs, res, lnw, lnb, h);
    else
      add_ln_kernel<kD, 4><<<kTok, 256, 0, stream>>>(part_out, res, lnw, lnb, h);

    // xz = h @ ipw^T   (392 x 3072, K=768)
    gemm_mfma<1, 0, false><<<dim3(7, 48, 1), 256, 0, stream>>>(
        h, kD, ipw, nullptr, xz, 2 * kDI, kTok, 2 * kDI, kD);

    // xdbl = silu(conv(xz)) @ xpw^T  (392 x 80, K=1536 split 24) + reduce
    gemm_xdbl_conv<<<dim3(7, 2, 24), 256, 0, stream>>>(xz, cw, cb, xpw, part_xdbl);
    reduce_kernel<<<(7840 + 255) / 256, 256, 0, stream>>>(part_xdbl, xdbl, 7840, 24);

    // dt = softplus(dtr @ dtw^T + dt_b)  (392 x 1536, K=48 zero-padded)
    gemm_mfma<1, 1, true><<<dim3(7, 24, 1), 256, 0, stream>>>(
        xdbl, 80, dtw, dtbv, dtb_, kDI, kTok, kDI, kDTR);

    // state-parallel scan (conv fused, 768 blocks) -> ybuf
    scan_state_kernel<<<dim3(96, kB), 256, 0, stream>>>(dtb_, xz, xdbl, cw, cb,
                                                        alog, dsk, ybuf);

    // y2 = (LN(ybuf)*slw+slb) * silu(z)
    ssm_ln_silu_kernel<<<kTok, 256, 0, stream>>>(ybuf, xz, slw, slb, y2);

    // out_proj partials: part_out[z] = y2 @ opw^T (z-th K-quarter)
    gemm_mfma<4, 0, false><<<dim3(7, 12, 4), 256, 0, stream>>>(
        y2, kDI, opw, nullptr, part_out, kD, kTok, kD, kDI);
  }

  // ---- latent = LN(res + sum part_out) ----
  add_ln_kernel<kD, 4><<<kTok, 256, 0, stream>>>(part_out, res, final_ln_w,
                                                 final_ln_b, latent);
}

// Round 14
// 1349.701 us; speedup vs baseline: 1.4408x; 1.0216x over previous
//
#include <hip/hip_runtime.h>
#include <cstdint>
#include <cstddef>

namespace {

constexpr int kD    = 768;
constexpr int kDI   = 1536;
constexpr int kN    = 16;
constexpr int kDTR  = 48;
constexpr int kL    = 196;
constexpr int kKeep = 49;
constexpr int kB    = 8;
constexpr int kTok  = kB * kKeep;   // 392
constexpr int kPatchRows = kB * kL; // 1568
constexpr float kEps = 1e-5f;

typedef __attribute__((ext_vector_type(8))) short short8;
typedef __attribute__((ext_vector_type(4))) float f32x4;

// f32 -> bf16 round-to-nearest-even
__device__ __forceinline__ short f2bf(float f) {
  unsigned u = __float_as_uint(f);
  return (short)((u + 0x7FFFu + ((u >> 16) & 1u)) >> 16);
}

__device__ __forceinline__ short8 pack8(float4 a, float4 b) {
  short8 r;
  r[0] = f2bf(a.x); r[1] = f2bf(a.y); r[2] = f2bf(a.z); r[3] = f2bf(a.w);
  r[4] = f2bf(b.x); r[5] = f2bf(b.y); r[6] = f2bf(b.z); r[7] = f2bf(b.w);
  return r;
}

__device__ __forceinline__ float silu(float x) { return x / (1.f + expf(-x)); }

// ---------------- block reduction (256 threads = 4 waves) ----------------
__device__ __forceinline__ float block_sum256(float x, float* sbuf) {
#pragma unroll
  for (int o = 32; o > 0; o >>= 1) x += __shfl_down(x, o, 64);
  int wid = threadIdx.x >> 6;
  if ((threadIdx.x & 63) == 0) sbuf[wid] = x;
  __syncthreads();
  float r = sbuf[0] + sbuf[1] + sbuf[2] + sbuf[3];
  __syncthreads();
  return r;
}

// ---------------- im2col for patch embedding ----------------
__global__ __launch_bounds__(256) void im2col_kernel(const float* __restrict__ imgs,
                                                     float* __restrict__ A2) {
  int idx = blockIdx.x * 256 + threadIdx.x;
  if (idx >= kPatchRows * kD) return;
  int col = idx % kD;
  int row = idx / kD;
  int b = row / kL, l = row % kL;
  int gy = l / 14, gx = l % 14;
  int c   = col >> 8;
  int rem = col & 255;
  int py = rem >> 4, px = rem & 15;
  A2[idx] = imgs[((b * 3 + c) * 224 + gy * 16 + py) * 224 + gx * 16 + px];
}

// ---------------- bf16 MFMA GEMM: C[M,N] = A[M,lda] @ W[N,K]^T (+bias) ------
// 64x64 tile, BK=64, 4 waves (2x2), 2x2 x mfma_f32_16x16x32_bf16 per wave.
// Double-buffered LDS, register prefetch of tile kt+1 before MFMA kt,
// ONE barrier per K-step (write goes to the buffer whose readers all passed
// the previous barrier).
// SPLIT==1: direct store (+bias). SPLIT>1: partial z -> C + z*M*N (dense).
template <int SPLIT>
__global__ __launch_bounds__(256) void gemm_mfma(const float* __restrict__ A, int lda,
                                                 const float* __restrict__ W,
                                                 const float* __restrict__ bias,
                                                 float* __restrict__ C, int ldc,
                                                 int M, int N, int K) {
  __shared__ __align__(16) short As[2][8][64][8];
  __shared__ __align__(16) short Bs[2][8][64][8];
  const int tid = threadIdx.x;
  const int bm = blockIdx.x * 64;
  const int bn = blockIdx.y * 64;
  const int kc = K / SPLIT;
  const int k0 = blockIdx.z * kc;
  const int nk = kc / 64;
  const int sr = tid >> 2;
  const int sq = tid & 3;
  const int lane = tid & 63;
  const int wm = ((tid >> 6) >> 1) * 32;
  const int wn = ((tid >> 6) & 1) * 32;
  const bool mok = (bm + sr) < M;
  const bool nok = (bn + sr) < N;
  const float* Ap = A + (size_t)(bm + sr) * lda + k0 + sq * 16;
  const float* Wp = W + (size_t)(bn + sr) * K + k0 + sq * 16;
  const float4 z4 = make_float4(0.f, 0.f, 0.f, 0.f);

  // tile 0 -> LDS[0]
  {
    float4 a0 = z4, a1 = z4, a2 = z4, a3 = z4;
    float4 w0 = z4, w1 = z4, w2 = z4, w3 = z4;
    if (mok) {
      a0 = *(const float4*)Ap;       a1 = *(const float4*)(Ap + 4);
      a2 = *(const float4*)(Ap + 8); a3 = *(const float4*)(Ap + 12);
    }
    if (nok) {
      w0 = *(const float4*)Wp;       w1 = *(const float4*)(Wp + 4);
      w2 = *(const float4*)(Wp + 8); w3 = *(const float4*)(Wp + 12);
    }
    *(short8*)&As[0][sq * 2][sr][0]     = pack8(a0, a1);
    *(short8*)&As[0][sq * 2 + 1][sr][0] = pack8(a2, a3);
    *(short8*)&Bs[0][sq * 2][sr][0]     = pack8(w0, w1);
    *(short8*)&Bs[0][sq * 2 + 1][sr][0] = pack8(w2, w3);
  }
  __syncthreads();

  f32x4 acc[2][2];
#pragma unroll
  for (int i = 0; i < 2; ++i)
#pragma unroll
    for (int j = 0; j < 2; ++j) acc[i][j] = (f32x4){0.f, 0.f, 0.f, 0.f};

  for (int kt = 0; kt < nk; ++kt) {
    const int cur = kt & 1;
    float4 na0 = z4, na1 = z4, na2 = z4, na3 = z4;
    float4 nw0 = z4, nw1 = z4, nw2 = z4, nw3 = z4;
    const bool more = (kt + 1) < nk;
    if (more) {  // issue next-tile loads BEFORE this tile's MFMA
      const float* ap = Ap + (kt + 1) * 64;
      const float* wp = Wp + (kt + 1) * 64;
      if (mok) {
        na0 = *(const float4*)ap;       na1 = *(const float4*)(ap + 4);
        na2 = *(const float4*)(ap + 8); na3 = *(const float4*)(ap + 12);
      }
      if (nok) {
        nw0 = *(const float4*)wp;       nw1 = *(const float4*)(wp + 4);
        nw2 = *(const float4*)(wp + 8); nw3 = *(const float4*)(wp + 12);
      }
    }
#pragma unroll
    for (int kh = 0; kh < 2; ++kh) {
      const int kg = kh * 4 + (lane >> 4);
      short8 af0 = *(const short8*)&As[cur][kg][wm + (lane & 15)][0];
      short8 af1 = *(const short8*)&As[cur][kg][wm + 16 + (lane & 15)][0];
      short8 bf0 = *(const short8*)&Bs[cur][kg][wn + (lane & 15)][0];
      short8 bf1 = *(const short8*)&Bs[cur][kg][wn + 16 + (lane & 15)][0];
      acc[0][0] = __builtin_amdgcn_mfma_f32_16x16x32_bf16(af0, bf0, acc[0][0], 0, 0, 0);
      acc[0][1] = __builtin_amdgcn_mfma_f32_16x16x32_bf16(af0, bf1, acc[0][1], 0, 0, 0);
      acc[1][0] = __builtin_amdgcn_mfma_f32_16x16x32_bf16(af1, bf0, acc[1][0], 0, 0, 0);
      acc[1][1] = __builtin_amdgcn_mfma_f32_16x16x32_bf16(af1, bf1, acc[1][1], 0, 0, 0);
    }
    if (more) {
      const int nxt = cur ^ 1;
      *(short8*)&As[nxt][sq * 2][sr][0]     = pack8(na0, na1);
      *(short8*)&As[nxt][sq * 2 + 1][sr][0] = pack8(na2, na3);
      *(short8*)&Bs[nxt][sq * 2][sr][0]     = pack8(nw0, nw1);
      *(short8*)&Bs[nxt][sq * 2 + 1][sr][0] = pack8(nw2, nw3);
      __syncthreads();
    }
  }

  const int mrow = (lane >> 4) * 4;
  const int ncol = lane & 15;
#pragma unroll
  for (int i2 = 0; i2 < 2; ++i2)
#pragma unroll
    for (int j2 = 0; j2 < 2; ++j2) {
      int n = bn + wn + j2 * 16 + ncol;
      if (n >= N) continue;
      float bv = (SPLIT == 1 && bias) ? bias[n] : 0.f;
#pragma unroll
      for (int r = 0; r < 4; ++r) {
        int m = bm + wm + i2 * 16 + mrow + r;
        if (m >= M) continue;
        float v = acc[i2][j2][r];
        if (SPLIT == 1) {
          C[(size_t)m * ldc + n] = v + bv;
        } else {
          C[(size_t)blockIdx.z * ((size_t)M * N) + (size_t)m * N + n] = v;
        }
      }
    }
}

// ------- xdbl GEMM with fused depthwise conv+SiLU on the A operand ---------
// xdbl_part[z][m][n] = (silu(conv(xz[:, :1536]))[m, k0:k0+64]) @ xpw[n, k0:k0+64]^T
__global__ __launch_bounds__(256) void gemm_xdbl_conv(const float* __restrict__ xz,
                                                      const float* __restrict__ cw,
                                                      const float* __restrict__ cb,
                                                      const float* __restrict__ W,
                                                      float* __restrict__ Cpart) {
  __shared__ __align__(16) short As[8][64][8];
  __shared__ __align__(16) short Bs[8][64][8];
  const int tid = threadIdx.x;
  const int bm = blockIdx.x * 64;
  const int bn = blockIdx.y * 64;
  const int k0 = blockIdx.z * 64;
  const int sr = tid >> 2;
  const int sq = tid & 3;
  const int lane = tid & 63;
  const int wm = ((tid >> 6) >> 1) * 32;
  const int wn = ((tid >> 6) & 1) * 32;
  const int m = bm + sr;
  const bool mok = m < kTok;
  const bool nok = (bn + sr) < 80;
  const float4 z4 = make_float4(0.f, 0.f, 0.f, 0.f);

  float4 a[4] = {z4, z4, z4, z4};
  if (mok) {
    const int b = m / kKeep, t = m % kKeep;
    const int dbase = k0 + sq * 16;
#pragma unroll
    for (int g = 0; g < 4; ++g) {
      const int d = dbase + g * 4;
      float4 cacc = *(const float4*)&cb[d];
      float4 c0 = *(const float4*)&cw[(d + 0) * 4];
      float4 c1 = *(const float4*)&cw[(d + 1) * 4];
      float4 c2 = *(const float4*)&cw[(d + 2) * 4];
      float4 c3 = *(const float4*)&cw[(d + 3) * 4];
      const float t0[4] = {c0.x, c0.y, c0.z, c0.w};
      const float t1[4] = {c1.x, c1.y, c1.z, c1.w};
      const float t2[4] = {c2.x, c2.y, c2.z, c2.w};
      const float t3[4] = {c3.x, c3.y, c3.z, c3.w};
#pragma unroll
      for (int j = 0; j < 4; ++j) {
        int tt = t - 3 + j;
        if (tt < 0) continue;
        float4 xv = *(const float4*)&xz[(size_t)(b * kKeep + tt) * 3072 + d];
        cacc.x += xv.x * t0[j];
        cacc.y += xv.y * t1[j];
        cacc.z += xv.z * t2[j];
        cacc.w += xv.w * t3[j];
      }
      cacc.x = silu(cacc.x); cacc.y = silu(cacc.y);
      cacc.z = silu(cacc.z); cacc.w = silu(cacc.w);
      a[g] = cacc;
    }
  }
  float4 w0 = z4, w1 = z4, w2 = z4, w3 = z4;
  if (nok) {
    const float* wp = W + (size_t)(bn + sr) * kDI + k0 + sq * 16;
    w0 = *(const float4*)wp;       w1 = *(const float4*)(wp + 4);
    w2 = *(const float4*)(wp + 8); w3 = *(const float4*)(wp + 12);
  }
  *(short8*)&As[sq * 2][sr][0]     = pack8(a[0], a[1]);
  *(short8*)&As[sq * 2 + 1][sr][0] = pack8(a[2], a[3]);
  *(short8*)&Bs[sq * 2][sr][0]     = pack8(w0, w1);
  *(short8*)&Bs[sq * 2 + 1][sr][0] = pack8(w2, w3);
  __syncthreads();

  f32x4 acc[2][2];
#pragma unroll
  for (int i = 0; i < 2; ++i)
#pragma unroll
    for (int j = 0; j < 2; ++j) acc[i][j] = (f32x4){0.f, 0.f, 0.f, 0.f};
#pragma unroll
  for (int kh = 0; kh < 2; ++kh) {
    const int kg = kh * 4 + (lane >> 4);
    short8 af0 = *(const short8*)&As[kg][wm + (lane & 15)][0];
    short8 af1 = *(const short8*)&As[kg][wm + 16 + (lane & 15)][0];
    short8 bf0 = *(const short8*)&Bs[kg][wn + (lane & 15)][0];
    short8 bf1 = *(const short8*)&Bs[kg][wn + 16 + (lane & 15)][0];
    acc[0][0] = __builtin_amdgcn_mfma_f32_16x16x32_bf16(af0, bf0, acc[0][0], 0, 0, 0);
    acc[0][1] = __builtin_amdgcn_mfma_f32_16x16x32_bf16(af0, bf1, acc[0][1], 0, 0, 0);
    acc[1][0] = __builtin_amdgcn_mfma_f32_16x16x32_bf16(af1, bf0, acc[1][0], 0, 0, 0);
    acc[1][1] = __builtin_amdgcn_mfma_f32_16x16x32_bf16(af1, bf1, acc[1][1], 0, 0, 0);
  }

  const int mrow = (lane >> 4) * 4;
  const int ncol = lane & 15;
#pragma unroll
  for (int i2 = 0; i2 < 2; ++i2)
#pragma unroll
    for (int j2 = 0; j2 < 2; ++j2) {
      int n = bn + wn + j2 * 16 + ncol;
      if (n >= 80) continue;
#pragma unroll
      for (int r = 0; r < 4; ++r) {
        int mm = bm + wm + i2 * 16 + mrow + r;
        if (mm >= kTok) continue;
        Cpart[(size_t)blockIdx.z * (kTok * 80) + (size_t)mm * 80 + n] =
            acc[i2][j2][r];
      }
    }
}

// ---------------- sum split-K partials: out = sum_z part[z] ----------------
__global__ __launch_bounds__(256) void reduce_kernel(const float* __restrict__ part,
                                                     float* __restrict__ out,
                                                     int total4, int Z) {
  int i = blockIdx.x * 256 + threadIdx.x;
  if (i >= total4) return;
  const float4* p = (const float4*)part;
  float4 s = p[i];
  for (int z = 1; z < Z; ++z) {
    float4 v = p[(size_t)z * total4 + i];
    s.x += v.x; s.y += v.y; s.z += v.z; s.w += v.w;
  }
  ((float4*)out)[i] = s;
}

// ---------------- argsort / mask ----------------
__global__ __launch_bounds__(256) void sort_kernel(const float* __restrict__ noise,
                                                   int* __restrict__ ids_keep,
                                                   float* __restrict__ mask_out,
                                                   float* __restrict__ idsr_out) {
  __shared__ float nb[kL];
  int b = blockIdx.x;
  int t = threadIdx.x;
  if (t < kL) nb[t] = noise[b * kL + t];
  __syncthreads();
  if (t < kL) {
    float v = nb[t];
    int rank = 0;
    for (int j = 0; j < kL; ++j) {
      float u = nb[j];
      rank += (u < v || (u == v && j < t)) ? 1 : 0;
    }
    if (rank < kKeep) ids_keep[b * kKeep + rank] = t;
    idsr_out[b * kL + t] = (float)rank;
    mask_out[b * kL + t] = (rank < kKeep) ? 0.f : 1.f;
  }
}

// ---------------- gather kept tokens (+ pos embed) ----------------
__global__ __launch_bounds__(256) void gather_kernel(const float* __restrict__ x0,
                                                     const int* __restrict__ ids_keep,
                                                     const float* __restrict__ pos,
                                                     float* __restrict__ hs) {
  int m = blockIdx.x;
  int b = m / kKeep, k = m % kKeep;
  int l = ids_keep[b * kKeep + k];
  const float* src = x0 + (size_t)(b * kL + l) * kD;
  const float* pp  = pos + (size_t)l * kD;
  float* dst = hs + (size_t)m * kD;
  for (int d = threadIdx.x; d < kD; d += 256) dst[d] = src[d] + pp[d];
}

// ------- res += sum_z part[z] ; out = LN(res)*w + b  (NP partials) ----------
template <int DD, int NP>
__global__ __launch_bounds__(256) void add_ln_kernel(const float* __restrict__ part,
                                                     float* __restrict__ res,
                                                     const float* __restrict__ w,
                                                     const float* __restrict__ b,
                                                     float* __restrict__ out) {
  constexpr int PT = DD / 256;
  __shared__ float sbuf[4];
  int m = blockIdx.x;
  int t = threadIdx.x;
  float v[PT];
  float s = 0.f;
#pragma unroll
  for (int i = 0; i < PT; ++i) {
    int d = t + i * 256;
    float acc = res[(size_t)m * DD + d];
#pragma unroll
    for (int z = 0; z < NP; ++z)
      acc += part[(size_t)z * (kTok * DD) + (size_t)m * DD + d];
    v[i] = acc;
    s += acc;
  }
  float mean = block_sum256(s, sbuf) * (1.f / DD);
  float s2 = 0.f;
#pragma unroll
  for (int i = 0; i < PT; ++i) { float d0 = v[i] - mean; s2 += d0 * d0; }
  float var = block_sum256(s2, sbuf) * (1.f / DD);
  float rstd = rsqrtf(var + kEps);
#pragma unroll
  for (int i = 0; i < PT; ++i) {
    int d = t + i * 256;
    res[(size_t)m * DD + d] = v[i];
    out[(size_t)m * DD + d] = (v[i] - mean) * rstd * w[d] + b[d];
  }
}

// ------ state-parallel selective scan with fused dt and conv ---------------
// block = 16 ch x 16 states = 256 thr; grid = (1536/16, 8) = 768 blocks.
// Phase 1 (parallel pre-pass): dt[t][c] = softplus(dtr[t] . dtw[d0+c] + dtb)
//   thread <-> (t-group, channel c); dtw row hoisted to 12 float4 regs.
// Phase 2 (recurrence): thread = (channel ch, state n); conv+SiLU recomputed
//   per lane (x16 redundant, cheap); y reduced over 16-state group via
//   shfl_xor; coalesced LDS-staged IO.
__global__ __launch_bounds__(256) void scan_state_kernel(
    const float* __restrict__ xz,    // [392][3072] (x half)
    const float* __restrict__ xdbl,  // [392][80] (dtr 0..47, B/C 48..79)
    const float* __restrict__ cw, const float* __restrict__ cb,
    const float* __restrict__ dtw,   // [1536][48]
    const float* __restrict__ dtbv,  // [1536]
    const float* __restrict__ A_log, const float* __restrict__ D_skip,
    float* __restrict__ y) {
  __shared__ __align__(16) float dtr_s[kKeep][kDTR];  // 9408 B
  __shared__ __align__(16) float dtw_s[16][52];       // 3328 B (pad: bank+16B)
  __shared__ float bcs[kKeep][32];                    // 6272 B
  __shared__ float dts[kKeep][16];                    // 3136 B
  __shared__ float xzs[kKeep][16];                    // 3136 B
  __shared__ float ys[kKeep][16];                     // 3136 B
  const int d0 = blockIdx.x * 16;
  const int b  = blockIdx.y;
  const int tid = threadIdx.x;
  // stage xdbl row (dtr + B/C), xz slice, dtw rows
  for (int i = tid; i < kKeep * 80; i += 256) {
    int t = i / 80, c = i % 80;
    float v = xdbl[(size_t)(b * kKeep + t) * 80 + c];
    if (c < kDTR) dtr_s[t][c] = v;
    else bcs[t][c - kDTR] = v;
  }
  for (int i = tid; i < kKeep * 16; i += 256) {
    int t = i >> 4, c = i & 15;
    xzs[t][c] = xz[(size_t)(b * kKeep + t) * 3072 + d0 + c];
  }
  for (int i = tid; i < 16 * kDTR; i += 256)
    dtw_s[i / kDTR][i % kDTR] = dtw[(size_t)(d0 + i / kDTR) * kDTR + i % kDTR];
  __syncthreads();

  // ---- phase 1: dt pre-pass (fully parallel) ----
  {
    const int c = tid & 15;          // channel within block
    const int tg = tid >> 4;         // t-group 0..15
    float4 wreg[12];
#pragma unroll
    for (int q = 0; q < 12; ++q) wreg[q] = *(const float4*)&dtw_s[c][q * 4];
    const float dtb0 = dtbv[d0 + c];
    for (int t = tg; t < kKeep; t += 16) {
      float acc = dtb0;
#pragma unroll
      for (int q = 0; q < 12; ++q) {
        float4 r = *(const float4*)&dtr_s[t][q * 4];
        acc += r.x * wreg[q].x + r.y * wreg[q].y +
               r.z * wreg[q].z + r.w * wreg[q].w;
      }
      dts[t][c] = (acc > 20.f) ? acc : log1pf(expf(acc));
    }
  }
  __syncthreads();

  // ---- phase 2: recurrence ----
  const int ch = tid >> 4;   // channel
  const int n  = tid & 15;   // state
  const int d  = d0 + ch;
  const float Aval = -expf(A_log[(size_t)d * kN + n]);
  const float dsk  = D_skip[d];
  const float4 cw4 = *(const float4*)&cw[d * 4];
  const float cb0  = cb[d];

  float s = 0.f;
  float w0 = 0.f, w1 = 0.f, w2 = 0.f;  // conv window
  for (int t = 0; t < kKeep; ++t) {
    float xin = xzs[t][ch];
    float cacc = cb0 + w0 * cw4.x + w1 * cw4.y + w2 * cw4.z + xin * cw4.w;
    w0 = w1; w1 = w2; w2 = xin;
    float xcv = silu(cacc);
    float dtv = dts[t][ch];
    s = expf(dtv * Aval) * s + (dtv * xcv) * bcs[t][n];
    float yp = s * bcs[t][16 + n];
    yp += __shfl_xor(yp, 1, 64);
    yp += __shfl_xor(yp, 2, 64);
    yp += __shfl_xor(yp, 4, 64);
    yp += __shfl_xor(yp, 8, 64);
    if (n == 0) ys[t][ch] = yp + dsk * xcv;
  }
  __syncthreads();
  for (int i = tid; i < kKeep * 16; i += 256)
    y[(size_t)(b * kKeep + (i >> 4)) * kDI + d0 + (i & 15)] = ys[i >> 4][i & 15];
}

// ---------------- y2 = (LN(y)*w+b) * silu(z) ----------------
__global__ __launch_bounds__(256) void ssm_ln_silu_kernel(const float* __restrict__ y,
                                                          const float* __restrict__ xz,
                                                          const float* __restrict__ w,
                                                          const float* __restrict__ b,
                                                          float* __restrict__ y2) {
  constexpr int PT = kDI / 256;  // 6
  __shared__ float sbuf[4];
  int m = blockIdx.x;
  int t = threadIdx.x;
  float v[PT];
  float s = 0.f;
#pragma unroll
  for (int i = 0; i < PT; ++i) {
    int d = t + i * 256;
    v[i] = y[(size_t)m * kDI + d];
    s += v[i];
  }
  float mean = block_sum256(s, sbuf) * (1.f / kDI);
  float s2 = 0.f;
#pragma unroll
  for (int i = 0; i < PT; ++i) { float d0 = v[i] - mean; s2 += d0 * d0; }
  float var = block_sum256(s2, sbuf) * (1.f / kDI);
  float rstd = rsqrtf(var + kEps);
#pragma unroll
  for (int i = 0; i < PT; ++i) {
    int d = t + i * 256;
    float z = xz[(size_t)m * 3072 + kDI + d];
    y2[(size_t)m * kDI + d] =
        ((v[i] - mean) * rstd * w[d] + b[d]) * silu(z);
  }
}

}  // namespace

extern "C" void kernel_launch(void* const* d_in, const int* in_sizes, int n_in,
                              void* d_out, int out_size, void* d_ws, size_t ws_size,
                              hipStream_t stream) {
  const float* imgs       = (const float*)d_in[0];
  const float* noise      = (const float*)d_in[1];
  const float* patch_w    = (const float*)d_in[2];
  const float* patch_b    = (const float*)d_in[3];
  const float* pos_embed  = (const float*)d_in[4];
  const float* ln_w       = (const float*)d_in[5];
  const float* ln_b       = (const float*)d_in[6];
  const float* in_proj_w  = (const float*)d_in[7];
  const float* conv_w     = (const float*)d_in[8];
  const float* conv_b     = (const float*)d_in[9];
  const float* x_proj_w   = (const float*)d_in[10];
  const float* dt_w       = (const float*)d_in[11];
  const float* dt_b       = (const float*)d_in[12];
  const float* A_log      = (const float*)d_in[13];
  const float* D_skip     = (const float*)d_in[14];
  const float* ssm_ln_w   = (const float*)d_in[15];
  const float* ssm_ln_b   = (const float*)d_in[16];
  const float* out_proj_w = (const float*)d_in[17];
  const float* final_ln_w = (const float*)d_in[18];
  const float* final_ln_b = (const float*)d_in[19];

  float* out      = (float*)d_out;
  float* latent   = out;                       // 392*768
  float* mask_out = out + 301056;              // 8*196
  float* idsr_out = out + 301056 + 1568;       // 8*196

  // workspace layout (floats)
  float* ws        = (float*)d_ws;
  float* hs        = ws;                    // 301056 (gather out, layer-0 "partial")
  float* res       = hs + 301056;           // 301056
  float* h         = res + 301056;          // 301056
  float* xz        = h + 301056;            // 1204224 (392x3072)
  float* xdbl      = xz + 1204224;          // 31360   (392x80)
  float* part_xdbl = xdbl + 31360;          // 24 x 31360 = 752640
  float* part_out  = part_xdbl + 752640;    // 4 x 301056 = 1204224
  float* ybuf      = part_out + 1204224;    // 602112
  float* y2        = ybuf + 602112;         // 602112
  int*   ids_keep  = (int*)(y2 + 602112);   // 392 ints
  // patch-stage aliases (time-disjoint)
  float* A2 = xz;          // 1568x768 = 1204224, exact fit
  float* x0 = part_xdbl;   // 1568x768 fits in part_xdbl+part_out (1956864)

  // ---- patch embedding: im2col + MFMA GEMM (bias = patch_b) ----
  {
    int tot = kPatchRows * kD;
    im2col_kernel<<<(tot + 255) / 256, 256, 0, stream>>>(imgs, A2);
    gemm_mfma<1><<<dim3(25, 12, 1), 256, 0, stream>>>(
        A2, kD, patch_w, patch_b, x0, kD, kPatchRows, kD, kD);
  }

  // ---- masking (argsort ranks) ----
  sort_kernel<<<kB, 256, 0, stream>>>(noise, ids_keep, mask_out, idsr_out);

  // ---- gather kept tokens + pos embed -> hs ----
  gather_kernel<<<kTok, 256, 0, stream>>>(x0, ids_keep, pos_embed, hs);

  // ---- res = 0 ----
  hipMemsetAsync(res, 0, (size_t)kTok * kD * sizeof(float), stream);

  // ---- 12 Mamba blocks ----
  for (int l = 0; l < 12; ++l) {
    const float* lnw  = ln_w  + (size_t)l * kD;
    const float* lnb  = ln_b  + (size_t)l * kD;
    const float* ipw  = in_proj_w  + (size_t)l * 2 * kDI * kD;
    const float* cw   = conv_w     + (size_t)l * kDI * 4;
    const float* cb   = conv_b     + (size_t)l * kDI;
    const float* xpw  = x_proj_w   + (size_t)l * (kDTR + 2 * kN) * kDI;
    const float* dtw  = dt_w       + (size_t)l * kDI * kDTR;
    const float* dtbv = dt_b       + (size_t)l * kDI;
    const float* alog = A_log      + (size_t)l * kDI * kN;
    const float* dsk  = D_skip     + (size_t)l * kDI;
    const float* slw  = ssm_ln_w   + (size_t)l * kDI;
    const float* slb  = ssm_ln_b   + (size_t)l * kDI;
    const float* opw  = out_proj_w + (size_t)l * kD * kDI;

    // res += (hs | out_proj partials) ; h = LN(res)
    if (l == 0)
      add_ln_kernel<kD, 1><<<kTok, 256, 0, stream>>>(hs, res, lnw, lnb, h);
    else
      add_ln_kernel<kD, 4><<<kTok, 256, 0, stream>>>(part_out, res, lnw, lnb, h);

    // xz = h @ ipw^T   (392 x 3072, K=768)
    gemm_mfma<1><<<dim3(7, 48, 1), 256, 0, stream>>>(
        h, kD, ipw, nullptr, xz, 2 * kDI, kTok, 2 * kDI, kD);

    // xdbl = silu(conv(xz)) @ xpw^T  (392 x 80, K=1536 split 24) + reduce
    gemm_xdbl_conv<<<dim3(7, 2, 24), 256, 0, stream>>>(xz, cw, cb, xpw, part_xdbl);
    reduce_kernel<<<(7840 + 255) / 256, 256, 0, stream>>>(part_xdbl, xdbl, 7840, 24);

    // state-parallel scan with fused dt + conv -> ybuf
    scan_state_kernel<<<dim3(96, kB), 256, 0, stream>>>(xz, xdbl, cw, cb, dtw,
                                                        dtbv, alog, dsk, ybuf);

    // y2 = (LN(ybuf)*slw+slb) * silu(z)
    ssm_ln_silu_kernel<<<kTok, 256, 0, stream>>>(ybuf, xz, slw, slb, y2);

    // out_proj partials: part_out[z] = y2 @ opw^T (z-th K-quarter)
    gemm_mfma<4><<<dim3(7, 12, 4), 256, 0, stream>>>(
        y2, kDI, opw, nullptr, part_out, kD, kTok, kD, kDI);
  }

  // ---- latent = LN(res + sum part_out) ----
  add_ln_kernel<kD, 4><<<kTok, 256, 0, stream>>>(part_out, res, final_ln_w,
                                                 final_ln_b, latent);
}